// Round 7
// baseline (91.720 us; speedup 1.0000x reference)
//
#include <hip/hip_runtime.h>
#include <stdint.h>

#define B_ 4
#define N_ 4096
#define Q_ 4096
#define K_ 32
#define E_ 32
#define R_ 16
#define F_ 53   // 3 rel_pos + 1 radius + 32 emb + 16 rbf + 1 dist

static constexpr int   NB   = 512;       // x-buckets per batch
static constexpr float XLO  = -64.0f;
static constexpr float INVW = 4.0f;      // bucket width 0.25

static constexpr int WAVES   = 16;
static constexpr int THREADS = WAVES * 64;   // 1024
static constexpr int QPB     = 32;           // 2 sorted queries per wave
static constexpr int CAP     = 128;          // per-query candidate capacity
static constexpr int TILE    = K_ * F_;      // 1696 floats
static constexpr int NSLOT   = 8;
static constexpr int POOLB   = (QPB * CAP * 4 > NSLOT * TILE * 4)
                             ? (QPB * CAP * 4) : (NSLOT * TILE * 4);

__device__ __host__ __forceinline__ int xbucket(float v) {
    int i = (int)floorf((v - XLO) * INVW);
    return i < 0 ? 0 : (i > NB - 1 ? NB - 1 : i);
}

__device__ __forceinline__ void bitonic_sort64_u32(unsigned int& v, int lane) {
    #pragma unroll
    for (int k = 2; k <= 64; k <<= 1) {
        #pragma unroll
        for (int j = k >> 1; j > 0; j >>= 1) {
            unsigned int o = __shfl_xor(v, j);
            const bool asc = ((lane & k) == 0);
            const bool lower = ((lane & j) == 0);
            unsigned int mn = v < o ? v : o;
            unsigned int mx = v < o ? o : v;
            v = (lower == asc) ? mn : mx;
        }
    }
}

__device__ __forceinline__ void bitonic_sort64_u64(unsigned long long& v, int lane) {
    #pragma unroll
    for (int k = 2; k <= 64; k <<= 1) {
        #pragma unroll
        for (int j = k >> 1; j > 0; j >>= 1) {
            unsigned long long o = __shfl_xor(v, j);
            const bool asc = ((lane & k) == 0);
            const bool lower = ((lane & j) == 0);
            unsigned long long mn = v < o ? v : o;
            unsigned long long mx = v < o ? o : v;
            v = (lower == asc) ? mn : mx;
        }
    }
}

__device__ __forceinline__ void merge64_u64(unsigned long long& best,
                                            unsigned long long c, int lane) {
    unsigned long long rev = __shfl(c, 63 - lane);
    unsigned long long v = best < rev ? best : rev;
    #pragma unroll
    for (int j = 32; j > 0; j >>= 1) {
        unsigned long long o = __shfl_xor(v, j);
        const bool lower = ((lane & j) == 0);
        unsigned long long mn = v < o ? v : o;
        unsigned long long mx = v < o ? o : v;
        v = lower ? mn : mx;
    }
    best = v;
}

// ---------------- prep: bucket atoms (AoS + offsets) and sort queries by x ----
__global__ __launch_bounds__(1024)
void prep_kernel(const float* __restrict__ coords,
                 const int* __restrict__ atom_mask,
                 const float* __restrict__ qpts,
                 const int* __restrict__ query_mask,
                 float4* __restrict__ aos,
                 float4* __restrict__ qaos,
                 unsigned int* __restrict__ bstart)
{
    __shared__ unsigned int hist[NB], incl[NB], cur[NB];
    const int b = blockIdx.x;
    const int tid = threadIdx.x;

    // ---- atoms ----
    if (tid < NB) hist[tid] = 0;
    __syncthreads();
    for (int i = tid; i < N_; i += 1024) {
        const bool mv = atom_mask[b * N_ + i] != 0;
        const float x = mv ? coords[(size_t)(b * N_ + i) * 3] : 1e30f;
        atomicAdd(&hist[xbucket(x)], 1u);
    }
    __syncthreads();
    if (tid < NB) incl[tid] = hist[tid];
    __syncthreads();
    for (int off = 1; off < NB; off <<= 1) {
        unsigned int v = 0;
        if (tid < NB && tid >= off) v = incl[tid - off];
        __syncthreads();
        if (tid < NB) incl[tid] += v;
        __syncthreads();
    }
    if (tid < NB) {
        const unsigned int ex = incl[tid] - hist[tid];
        cur[tid] = ex;
        bstart[b * (NB + 1) + tid] = ex;
    }
    if (tid == 0) bstart[b * (NB + 1) + NB] = N_;
    __syncthreads();
    for (int i = tid; i < N_; i += 1024) {
        const float* c = coords + (size_t)(b * N_ + i) * 3;
        const bool mv = atom_mask[b * N_ + i] != 0;
        const float nx = mv ? -c[0] : -1e30f;
        const float ny = mv ? -c[1] : -1e30f;
        const float nz = mv ? -c[2] : -1e30f;
        const int bk = xbucket(-nx);
        const unsigned int pos = atomicAdd(&cur[bk], 1u);
        aos[(size_t)b * N_ + pos] =
            make_float4(nx, ny, nz, __uint_as_float((unsigned int)i));
    }
    __syncthreads();

    // ---- queries (bucket-sort for x-locality; exact order irrelevant) ----
    if (tid < NB) hist[tid] = 0;
    __syncthreads();
    for (int i = tid; i < Q_; i += 1024)
        atomicAdd(&hist[xbucket(qpts[(size_t)(b * Q_ + i) * 3])], 1u);
    __syncthreads();
    if (tid < NB) incl[tid] = hist[tid];
    __syncthreads();
    for (int off = 1; off < NB; off <<= 1) {
        unsigned int v = 0;
        if (tid < NB && tid >= off) v = incl[tid - off];
        __syncthreads();
        if (tid < NB) incl[tid] += v;
        __syncthreads();
    }
    if (tid < NB) cur[tid] = incl[tid] - hist[tid];
    __syncthreads();
    for (int i = tid; i < Q_; i += 1024) {
        const float* q = qpts + (size_t)(b * Q_ + i) * 3;
        const float qx = q[0], qy = q[1], qz = q[2];
        const unsigned int qm = (query_mask[b * Q_ + i] != 0) ? 1u : 0u;
        const unsigned int pos = atomicAdd(&cur[xbucket(qx)], 1u);
        qaos[(size_t)b * Q_ + pos] =
            make_float4(qx, qy, qz, __uint_as_float((unsigned int)i | (qm << 16)));
    }
}

// ---------------- main kernel ----------------
__global__ __launch_bounds__(THREADS, 8)
void lfb_kernel(const float* __restrict__ coords,
                const int* __restrict__ atom_types,
                const float* __restrict__ radii,
                const float* __restrict__ embed,
                const float* __restrict__ centers,
                const float4* __restrict__ aos,
                const float4* __restrict__ qaos,
                const unsigned int* __restrict__ bstart,
                float* __restrict__ out)
{
    __shared__ __align__(16) unsigned char pool[POOLB]; // cand idx / stage slots

    const int tid  = threadIdx.x;
    const int lane = tid & 63;
    const int wv   = tid >> 6;
    const int b    = blockIdx.x >> 7;                // 128 blocks per batch
    const int base32 = (blockIdx.x & 127) * QPB;     // sorted-query base

    const float4* aosb = aos + (size_t)b * N_;
    const unsigned int* bs = bstart + b * (NB + 1);

    // this wave's two x-adjacent sorted queries
    const float4 qa = qaos[(size_t)b * Q_ + base32 + 2 * wv];
    const float4 qb = qaos[(size_t)b * Q_ + base32 + 2 * wv + 1];
    const float qxA = qa.x, qyA = qa.y, qzA = qa.z;
    const float qxB = qb.x, qyB = qb.y, qzB = qb.z;
    const unsigned int wA = __float_as_uint(qa.w);
    const unsigned int wB = __float_as_uint(qb.w);
    const int origqA = (int)(wA & 0xFFFFu), origqB = (int)(wB & 0xFFFFu);
    const bool qmA = (wA >> 16) & 1u, qmB = (wB >> 16) & 1u;

    const float INFf = __uint_as_float(0x7F800000u);

    // initial radius heuristic ~ local 32-NN radius for N(0,10)^3 data
    const float dotA = qxA * qxA + qyA * qyA + qzA * qzA;
    const float dotB = qxB * qxB + qyB * qyB + qzB * qzB;
    float rA = fminf(3.2f * __expf(dotA * (1.0f / 600.0f)), 40.0f);
    float rB = fminf(3.2f * __expf(dotB * (1.0f / 600.0f)), 40.0f);

    // ---- pass 1 (+ widen loop): lane-minima over union x-window ----
    int s = 0, e = 0;
    unsigned int TsA, TsB;
    for (;;) {
        const int lo = min(xbucket(qxA - rA), xbucket(qxB - rB));
        const int hi = max(xbucket(qxA + rA), xbucket(qxB + rB));
        s = (int)bs[lo];
        e = (int)bs[hi + 1];
        float mA = INFf, mB = INFf;
        for (int bi = s; bi < e; bi += 256) {
            float4 a[4];
            #pragma unroll
            for (int u = 0; u < 4; ++u) {
                const int i = bi + u * 64 + lane;
                a[u] = aosb[i < e ? i : e - 1];
            }
            #pragma unroll
            for (int u = 0; u < 4; ++u) {
                const int i = bi + u * 64 + lane;
                float dx = qxA + a[u].x, dy = qyA + a[u].y, dz = qzA + a[u].z;
                const float sA = fmaf(dz, dz, fmaf(dy, dy, dx * dx));
                dx = qxB + a[u].x; dy = qyB + a[u].y; dz = qzB + a[u].z;
                const float sB = fmaf(dz, dz, fmaf(dy, dy, dx * dx));
                if (i < e) { mA = fminf(mA, sA); mB = fminf(mB, sB); }
            }
        }
        unsigned int ua = __float_as_uint(mA), ub = __float_as_uint(mB);
        bitonic_sort64_u32(ua, lane);
        bitonic_sort64_u32(ub, lane);
        TsA = __shfl(ua, 31);
        TsB = __shfl(ub, 31);
        // coverage invariant: sqrt(Ts*(1+eps)) <= r  =>  window holds all top-32
        const bool okA = __uint_as_float(TsA) <= 0.999f * rA * rA;
        const bool okB = __uint_as_float(TsB) <= 0.999f * rB * rB;
        if ((okA && okB) || (lo == 0 && hi == NB - 1)) break;
        if (!okA) rA *= 2.0f;
        if (!okB) rB *= 2.0f;
    }
    const unsigned int STA = TsA + 64u;   // fma-vs-exact slop (superset guarantee)
    const unsigned int STB = TsB + 64u;   // Ts=inf floods -> cnt>CAP -> fallback

    // ---- pass 2: ballot-collect window positions per query ----
    unsigned int* poolu = reinterpret_cast<unsigned int*>(pool);
    unsigned int* cbA = poolu + (size_t)(wv * 2 + 0) * CAP;
    unsigned int* cbB = poolu + (size_t)(wv * 2 + 1) * CAP;
    const unsigned long long lt = (1ull << lane) - 1ull;
    int cntA = 0, cntB = 0;
    for (int bi = s; bi < e; bi += 256) {
        float4 a[4];
        #pragma unroll
        for (int u = 0; u < 4; ++u) {
            const int i = bi + u * 64 + lane;
            a[u] = aosb[i < e ? i : e - 1];
        }
        #pragma unroll
        for (int u = 0; u < 4; ++u) {
            const int i = bi + u * 64 + lane;
            const bool ok = i < e;
            float dx = qxA + a[u].x, dy = qyA + a[u].y, dz = qzA + a[u].z;
            const float sA = fmaf(dz, dz, fmaf(dy, dy, dx * dx));
            dx = qxB + a[u].x; dy = qyB + a[u].y; dz = qzB + a[u].z;
            const float sB = fmaf(dz, dz, fmaf(dy, dy, dx * dx));
            const bool pA = ok && (__float_as_uint(sA) <= STA);
            unsigned long long mm = __ballot(pA);
            if (pA) {
                const int sl = cntA + __popcll(mm & lt);
                if (sl < CAP) cbA[sl] = (unsigned int)i;
            }
            cntA += __popcll(mm);
            const bool pB = ok && (__float_as_uint(sB) <= STB);
            mm = __ballot(pB);
            if (pB) {
                const int sl = cntB + __popcll(mm & lt);
                if (sl < CAP) cbB[sl] = (unsigned int)i;
            }
            cntB += __popcll(mm);
        }
    }

    // ---- pass 3 / fallback: exact (d_bits, orig_idx) top-32 ----
    auto select_top32 = [&](const unsigned int* cbuf, int cnt,
                            float qx, float qy, float qz) -> unsigned long long {
        if (cnt <= CAP) {
            unsigned long long best = ~0ull;
            const int nch = (cnt + 63) >> 6;
            for (int c = 0; c < nch; ++c) {
                const int slot = c * 64 + lane;
                unsigned long long v = ~0ull;
                if (slot < cnt) {
                    const float4 a = aosb[cbuf[slot]];
                    // exact reference path: rn ops, fixed association, eps, CR sqrt
                    const float dx = __fadd_rn(qx, a.x);
                    const float dy = __fadd_rn(qy, a.y);
                    const float dz = __fadd_rn(qz, a.z);
                    const float sv = __fadd_rn(
                        __fadd_rn(__fmul_rn(dx, dx), __fmul_rn(dy, dy)),
                        __fmul_rn(dz, dz));
                    const float d = __fsqrt_rn(__fadd_rn(sv, 1e-12f));
                    v = ((unsigned long long)__float_as_uint(d) << 32)
                      | __float_as_uint(a.w);
                }
                bitonic_sort64_u64(v, lane);
                if (c == 0) best = v;
                else        merge64_u64(best, v, lane);
            }
            return best;
        }
        // fallback (degenerate masks / flooded threshold): exact full-N scan
        unsigned long long key = ~0ull;
        for (int bi = 0; bi < N_; bi += 64) {
            const float4 a = aosb[bi + lane];
            const float dx = __fadd_rn(qx, a.x);
            const float dy = __fadd_rn(qy, a.y);
            const float dz = __fadd_rn(qz, a.z);
            const float sv = __fadd_rn(
                __fadd_rn(__fmul_rn(dx, dx), __fmul_rn(dy, dy)),
                __fmul_rn(dz, dz));
            const float d = __fsqrt_rn(__fadd_rn(sv, 1e-12f));
            const unsigned long long cand =
                ((unsigned long long)__float_as_uint(d) << 32)
                | __float_as_uint(a.w);
            const unsigned long long T = __shfl(key, 31);
            unsigned long long m = __ballot(cand < T);
            while (m) {
                const int src = __ffsll(m) - 1;
                m &= m - 1;
                const unsigned long long nk = __shfl(cand, src);
                const unsigned long long up = __shfl_up(key, 1);
                if (lane < K_) {
                    const unsigned long long repl =
                        (lane == 0) ? nk : (up <= nk ? nk : up);
                    key = (key <= nk) ? key : repl;
                }
            }
        }
        return key;
    };

    const unsigned long long keyA = select_top32(cbA, cntA, qxA, qyA, qzA);
    const unsigned long long keyB = select_top32(cbB, cntB, qxB, qyB, qzB);

    const size_t BQK = (size_t)B_ * Q_ * K_;
    float* out_feat = out;
    float* out_mask = out + BQK * (size_t)F_;
    float* out_idx  = out_mask + BQK;
    float* out_dist = out_idx + BQK;

    const int flatqA = b * Q_ + origqA;
    const int flatqB = b * Q_ + origqB;

    // scalar outputs before the stage overlay barrier
    if (lane < K_) {
        {
            const float d = __uint_as_float((unsigned int)(keyA >> 32));
            const int  id = (int)(keyA & 0xFFFFFFFFull);
            const bool am = ((unsigned int)(keyA >> 32)) < 0x7F800000u;
            const bool nm = am && (d <= 5.0f) && qmA;
            const size_t o = (size_t)flatqA * K_ + lane;
            out_mask[o] = nm ? 1.0f : 0.0f;
            out_idx[o]  = am ? (float)id : -1.0f;
            out_dist[o] = nm ? d : 0.0f;
        }
        {
            const float d = __uint_as_float((unsigned int)(keyB >> 32));
            const int  id = (int)(keyB & 0xFFFFFFFFull);
            const bool am = ((unsigned int)(keyB >> 32)) < 0x7F800000u;
            const bool nm = am && (d <= 5.0f) && qmB;
            const size_t o = (size_t)flatqB * K_ + lane;
            out_mask[o] = nm ? 1.0f : 0.0f;
            out_idx[o]  = am ? (float)id : -1.0f;
            out_dist[o] = nm ? d : 0.0f;
        }
    }

    __syncthreads();   // all cand-buffer reads done before stage overlay

    // ---- feature build: NSLOT stage slots, 4 barrier rounds ----
    auto build_and_store = [&](int flatq, unsigned long long key,
                               float qx, float qy, float qz, bool qm,
                               float* slotp) {
        const float d_l  = __uint_as_float((unsigned int)(key >> 32));
        const int   id_l = (int)(key & 0xFFFFFFFFull) & (N_ - 1);
        const bool  am_l = ((unsigned int)(key >> 32)) < 0x7F800000u;
        const bool  nm_l = am_l && (d_l <= 5.0f) && qm;

        if (lane < K_) {
            float* f = slotp + lane * F_;
            const float* cp = coords + (size_t)(b * N_ + id_l) * 3;
            f[0] = nm_l ? __fsub_rn(qx, cp[0]) : 0.0f;
            f[1] = nm_l ? __fsub_rn(qy, cp[1]) : 0.0f;
            f[2] = nm_l ? __fsub_rn(qz, cp[2]) : 0.0f;
            f[3] = nm_l ? radii[b * N_ + id_l] : 0.0f;

            const int t = atom_types[b * N_ + id_l];
            const float4* er4 = (const float4*)(embed + t * E_);
            #pragma unroll
            for (int ei = 0; ei < E_ / 4; ++ei) {
                const float4 v = er4[ei];
                f[4 + ei * 4 + 0] = nm_l ? v.x : 0.0f;
                f[4 + ei * 4 + 1] = nm_l ? v.y : 0.0f;
                f[4 + ei * 4 + 2] = nm_l ? v.z : 0.0f;
                f[4 + ei * 4 + 3] = nm_l ? v.w : 0.0f;
            }

            const float NG = -(float)(256.0 / 25.0);   // -RBF_GAMMA
            #pragma unroll
            for (int rr = 0; rr < R_; ++rr) {
                const float dd = __fsub_rn(d_l, centers[rr]);
                const float a2 = __fmul_rn(dd, dd);
                f[36 + rr] = nm_l ? expf(__fmul_rn(NG, a2)) : 0.0f;
            }
            f[52] = nm_l ? d_l : 0.0f;
        }
        // same-wave LDS in-order: copy sees this wave's writes without a barrier
        const float4* s4 = (const float4*)slotp;
        float4* d4 = (float4*)(out_feat + (size_t)flatq * (size_t)TILE);
        for (int t4 = lane; t4 < TILE / 4; t4 += 64) d4[t4] = s4[t4];
    };

    float* stagef = reinterpret_cast<float*>(pool);
    for (int r = 0; r < 4; ++r) {
        if ((wv >> 3) == (r & 1)) {
            float* slotp = stagef + (size_t)(wv & (NSLOT - 1)) * TILE;
            if (r < 2) build_and_store(flatqA, keyA, qxA, qyA, qzA, qmA, slotp);
            else       build_and_store(flatqB, keyB, qxB, qyB, qzB, qmB, slotp);
        }
        __syncthreads();
    }
}

extern "C" void kernel_launch(void* const* d_in, const int* in_sizes, int n_in,
                              void* d_out, int out_size, void* d_ws, size_t ws_size,
                              hipStream_t stream) {
    const float* coords     = (const float*)d_in[0];
    const int*   atom_types = (const int*)d_in[1];
    const float* radii      = (const float*)d_in[2];
    const float* qpts       = (const float*)d_in[3];
    const int*   atom_mask  = (const int*)d_in[4];
    const int*   query_mask = (const int*)d_in[5];
    const float* embed      = (const float*)d_in[6];
    const float* centers    = (const float*)d_in[7];

    float4* aos  = (float4*)d_ws;                       // B*N float4
    float4* qaos = aos + (size_t)B_ * N_;               // B*Q float4
    unsigned int* bstart = (unsigned int*)(qaos + (size_t)B_ * Q_);

    prep_kernel<<<B_, 1024, 0, stream>>>(coords, atom_mask, qpts, query_mask,
                                         aos, qaos, bstart);

    dim3 grid((B_ * Q_) / QPB);
    dim3 block(THREADS);
    lfb_kernel<<<grid, block, 0, stream>>>(coords, atom_types, radii,
                                           embed, centers, aos, qaos, bstart,
                                           (float*)d_out);
}